// Round 1
// baseline (232.862 us; speedup 1.0000x reference)
//
#include <hip/hip_runtime.h>
#include <hip/hip_bf16.h>
#include <cmath>

typedef __bf16 bf16;
typedef __attribute__((ext_vector_type(8))) __bf16 bf16x8;
typedef __attribute__((ext_vector_type(4))) __bf16 bf16x4;
typedef __attribute__((ext_vector_type(4))) float f32x4;

constexpr int S  = 2048;
constexpr int E  = 1024;
constexpr int H  = 16;
constexpr int D  = 64;
constexpr int B  = 2;
constexpr int M  = B * S;   // 4096 rows
constexpr int N3 = 3 * E;   // 3072

static __device__ __forceinline__ void gload16(const void* g, void* l) {
  __builtin_amdgcn_global_load_lds((const __attribute__((address_space(1))) void*)g,
                                   (__attribute__((address_space(3))) void*)l, 16, 0, 0);
}

// ---------- f32 -> bf16 elementwise (vectorized, G13) ----------
__global__ void k_cvt(const float* __restrict__ in, bf16* __restrict__ out) {
  const int i = (blockIdx.x * blockDim.x + threadIdx.x) * 4;
  const float4 v = *(const float4*)(in + i);
  bf16x4 o = { (bf16)v.x, (bf16)v.y, (bf16)v.z, (bf16)v.w };
  *(bf16x4*)(out + i) = o;
}

// ---------- f32 [R][C] -> bf16 [C][R] (LDS tile transpose) ----------
__global__ void k_transpose_cvt(const float* __restrict__ in, bf16* __restrict__ out,
                                int R, int C) {
  __shared__ float t[32][33];
  const int c0 = blockIdx.x * 32, r0 = blockIdx.y * 32;
  const int tx = threadIdx.x, ty = threadIdx.y;
  #pragma unroll
  for (int j = 0; j < 32; j += 8)
    t[ty + j][tx] = in[(size_t)(r0 + ty + j) * C + c0 + tx];
  __syncthreads();
  #pragma unroll
  for (int j = 0; j < 32; j += 8)
    out[(size_t)(c0 + ty + j) * R + r0 + tx] = (bf16)t[tx][ty + j];
}

// ---------- GEMM: C[M][N] = A[M][K](bf16) * Bt[N][K](bf16)^T + bias ----------
// 128x128 tile, BK=64, 4 waves (2x2), 16x16x32 bf16 MFMA.
// LDS tiles XOR-swizzled (byte ^= (row&7)<<4) via pre-swizzled global source (rule #21).
// EPI==0: scatter to Q[B,H,S,D], K[B,H,S,D], V^T[B,H,D,S] (all bf16)
// EPI==1: out fp32 [M][E]
template<int EPI>
__global__ __launch_bounds__(256) void k_gemm(
    const bf16* __restrict__ A, const bf16* __restrict__ Bt,
    const float* __restrict__ bias, float* __restrict__ outF,
    bf16* __restrict__ oQ, bf16* __restrict__ oK, bf16* __restrict__ oV, int Kdim)
{
  __shared__ __align__(16) char lA[128 * 128];
  __shared__ __align__(16) char lB[128 * 128];
  const int tid = threadIdx.x;
  const int lane = tid & 63, w = tid >> 6;
  const int wm = w >> 1, wn = w & 1;
  const int bn0 = blockIdx.x * 128, bm0 = blockIdx.y * 128;
  f32x4 acc[4][4] = {};

  const int nkt = Kdim >> 6;
  for (int kt = 0; kt < nkt; ++kt) {
    __syncthreads();
    const int k0 = kt << 6;
    #pragma unroll
    for (int p = 0; p < 4; ++p) {
      const int o = p * 4096 + w * 1024 + lane * 16;  // linear byte in tile
      const int row = o >> 7;
      const int cb = o & 127;
      const int lk = (cb ^ ((row & 7) << 4)) >> 1;    // inverse-swizzled source col (elems)
      gload16(A + (size_t)(bm0 + row) * Kdim + k0 + lk, lA + p * 4096 + w * 1024);
      gload16(Bt + (size_t)(bn0 + row) * Kdim + k0 + lk, lB + p * 4096 + w * 1024);
    }
    asm volatile("s_waitcnt vmcnt(0)" ::: "memory");
    __syncthreads();

    #pragma unroll
    for (int kk = 0; kk < 2; ++kk) {
      bf16x8 af[4], bfr[4];
      #pragma unroll
      for (int f = 0; f < 4; ++f) {
        const int ra = wm * 64 + f * 16 + (lane & 15);
        af[f] = *(const bf16x8*)(lA + ra * 128 +
                 ((kk * 64 + ((lane >> 4) << 4)) ^ ((ra & 7) << 4)));
        const int rb = wn * 64 + f * 16 + (lane & 15);
        bfr[f] = *(const bf16x8*)(lB + rb * 128 +
                 ((kk * 64 + ((lane >> 4) << 4)) ^ ((rb & 7) << 4)));
      }
      #pragma unroll
      for (int i = 0; i < 4; ++i)
        #pragma unroll
        for (int j = 0; j < 4; ++j)
          acc[i][j] = __builtin_amdgcn_mfma_f32_16x16x32_bf16(af[i], bfr[j], acc[i][j], 0, 0, 0);
    }
  }

  // epilogue; C/D layout: col = lane&15, row = (lane>>4)*4 + reg
  #pragma unroll
  for (int i = 0; i < 4; ++i) {
    #pragma unroll
    for (int j = 0; j < 4; ++j) {
      const int n = bn0 + wn * 64 + j * 16 + (lane & 15);
      const float bv = bias[n];
      #pragma unroll
      for (int r = 0; r < 4; ++r) {
        const int m = bm0 + wm * 64 + i * 16 + ((lane >> 4) << 2) + r;
        const float v = acc[i][j][r] + bv;
        if constexpr (EPI == 0) {
          const int b = m >> 11, s = m & (S - 1);
          const int which = n >> 10, c = n & (E - 1);
          const int h = c >> 6, d = c & 63;
          const size_t bh = (size_t)b * H + h;
          if (which == 0)      oQ[(bh * S + s) * D + d] = (bf16)v;
          else if (which == 1) oK[(bh * S + s) * D + d] = (bf16)v;
          else                 oV[(bh * D + d) * S + s] = (bf16)v;
        } else {
          outF[(size_t)m * E + n] = v;
        }
      }
    }
  }
}

// ---------- flash attention (causal) ----------
// grid (S/64, B*H), 256 thr = 4 waves; each wave owns 16 q-rows.
// K tile [64k][64d], V^T tile [64d][64k] in swizzled LDS; P via wave-private swizzled LDS.
__global__ __launch_bounds__(256) void k_attn(
    const bf16* __restrict__ Qb, const bf16* __restrict__ Kb, const bf16* __restrict__ Vt,
    bf16* __restrict__ AO, const int* __restrict__ cmask)
{
  __shared__ __align__(16) char lK[64 * 128];
  __shared__ __align__(16) char lV[64 * 128];
  __shared__ __align__(16) char lP[4][16 * 128];
  const int tid = threadIdx.x, lane = tid & 63, w = tid >> 6;
  const int bh = blockIdx.y;
  const int qb = blockIdx.x;
  const int q0 = qb * 64;
  const int causal = cmask[0];
  const bf16* Qh = Qb + (size_t)bh * S * D;
  const bf16* Kh = Kb + (size_t)bh * S * D;
  const bf16* Vh = Vt + (size_t)bh * D * S;
  char* lPw = lP[w];

  // Q fragments in registers (A-operand: row=lane&15, k=(lane>>4)*8..)
  const int qrow = q0 + w * 16 + (lane & 15);
  bf16x8 qf[2];
  qf[0] = *(const bf16x8*)(Qh + (size_t)qrow * D + ((lane >> 4) << 3));
  qf[1] = *(const bf16x8*)(Qh + (size_t)qrow * D + 32 + ((lane >> 4) << 3));

  f32x4 oacc[4] = {};
  float mrow[4], lrow[4];
  #pragma unroll
  for (int i = 0; i < 4; ++i) { mrow[i] = -INFINITY; lrow[i] = 0.f; }

  const int myq = q0 + w * 16 + ((lane >> 4) << 2);
  const int nkt = causal ? (qb + 1) : (S / 64);

  for (int kt = 0; kt < nkt; ++kt) {
    __syncthreads();
    #pragma unroll
    for (int p = 0; p < 2; ++p) {
      const int o = p * 4096 + w * 1024 + lane * 16;
      const int row = o >> 7;
      const int cb = o & 127;
      const int lk = (cb ^ ((row & 7) << 4)) >> 1;
      gload16(Kh + (size_t)(kt * 64 + row) * D + lk, lK + p * 4096 + w * 1024);
      gload16(Vh + (size_t)row * S + kt * 64 + lk,   lV + p * 4096 + w * 1024);
    }
    asm volatile("s_waitcnt vmcnt(0)" ::: "memory");
    __syncthreads();

    // QK^T: scores 16q x 64k per wave
    f32x4 sc[4] = {};
    #pragma unroll
    for (int kk = 0; kk < 2; ++kk) {
      #pragma unroll
      for (int f = 0; f < 4; ++f) {
        const int rk = f * 16 + (lane & 15);
        const bf16x8 kf = *(const bf16x8*)(lK + rk * 128 +
                          ((kk * 64 + ((lane >> 4) << 4)) ^ ((rk & 7) << 4)));
        sc[f] = __builtin_amdgcn_mfma_f32_16x16x32_bf16(qf[kk], kf, sc[f], 0, 0, 0);
      }
    }

    // mask (before scale, matching ref; -inf is scale-invariant) + scale 1/8
    #pragma unroll
    for (int f = 0; f < 4; ++f) {
      const int kg = kt * 64 + f * 16 + (lane & 15);
      #pragma unroll
      for (int i = 0; i < 4; ++i) {
        float s = sc[f][i] * 0.125f;
        if (causal && kg > myq + i) s = -INFINITY;
        sc[f][i] = s;
      }
    }

    // online softmax: row reduce over 16 lanes (low 4 lane bits)
    float tmax[4];
    #pragma unroll
    for (int i = 0; i < 4; ++i)
      tmax[i] = fmaxf(fmaxf(sc[0][i], sc[1][i]), fmaxf(sc[2][i], sc[3][i]));
    #pragma unroll
    for (int x = 1; x < 16; x <<= 1)
      #pragma unroll
      for (int i = 0; i < 4; ++i)
        tmax[i] = fmaxf(tmax[i], __shfl_xor(tmax[i], x, 64));

    float mnew[4], corr[4];
    #pragma unroll
    for (int i = 0; i < 4; ++i) {
      mnew[i] = fmaxf(mrow[i], tmax[i]);
      corr[i] = __expf(mrow[i] - mnew[i]);   // first tile: exp(-inf)=0
    }

    float psum[4] = {0.f, 0.f, 0.f, 0.f};
    #pragma unroll
    for (int f = 0; f < 4; ++f) {
      #pragma unroll
      for (int i = 0; i < 4; ++i) {
        const float p = __expf(sc[f][i] - mnew[i]);
        psum[i] += p;
        const int pr = ((lane >> 4) << 2) + i;
        const int pcb = (((lane & 15) + 16 * f) << 1) ^ ((pr & 7) << 4);
        *(bf16*)(lPw + pr * 128 + pcb) = (bf16)p;
      }
    }
    #pragma unroll
    for (int x = 1; x < 16; x <<= 1)
      #pragma unroll
      for (int i = 0; i < 4; ++i)
        psum[i] += __shfl_xor(psum[i], x, 64);

    #pragma unroll
    for (int i = 0; i < 4; ++i) {
      lrow[i] = lrow[i] * corr[i] + psum[i];
      mrow[i] = mnew[i];
    }
    #pragma unroll
    for (int fd = 0; fd < 4; ++fd)
      #pragma unroll
      for (int i = 0; i < 4; ++i)
        oacc[fd][i] *= corr[i];

    // PV: out[16q][64d] += P[16,64] @ V[64,64]
    #pragma unroll
    for (int kk = 0; kk < 2; ++kk) {
      const int pr = lane & 15;
      const bf16x8 pa = *(const bf16x8*)(lPw + pr * 128 +
                        ((kk * 64 + ((lane >> 4) << 4)) ^ ((pr & 7) << 4)));
      #pragma unroll
      for (int fd = 0; fd < 4; ++fd) {
        const int rv = fd * 16 + (lane & 15);
        const bf16x8 vf = *(const bf16x8*)(lV + rv * 128 +
                          ((kk * 64 + ((lane >> 4) << 4)) ^ ((rv & 7) << 4)));
        oacc[fd] = __builtin_amdgcn_mfma_f32_16x16x32_bf16(pa, vf, oacc[fd], 0, 0, 0);
      }
    }
  }

  // normalize + write AO[B,S,E] bf16
  const int b = bh >> 4, h = bh & 15;
  #pragma unroll
  for (int fd = 0; fd < 4; ++fd) {
    #pragma unroll
    for (int i = 0; i < 4; ++i) {
      const int qg = myq + i;
      const int d = fd * 16 + (lane & 15);
      const float v = oacc[fd][i] / lrow[i];
      AO[((size_t)(b * S + qg)) * E + h * D + d] = (bf16)v;
    }
  }
}

extern "C" void kernel_launch(void* const* d_in, const int* in_sizes, int n_in,
                              void* d_out, int out_size, void* d_ws, size_t ws_size,
                              hipStream_t stream) {
  (void)in_sizes; (void)n_in; (void)out_size; (void)ws_size;
  const float* x     = (const float*)d_in[0];
  const float* W_in  = (const float*)d_in[1];
  const float* b_in  = (const float*)d_in[2];
  const float* W_out = (const float*)d_in[3];
  const float* b_out = (const float*)d_in[4];
  const int*   cmask = (const int*)d_in[5];

  // workspace layout (48 MB total)
  char* ws = (char*)d_ws;
  bf16* xb    = (bf16*)ws; ws += (size_t)M * E * 2;        // 8 MB
  bf16* wtin  = (bf16*)ws; ws += (size_t)N3 * E * 2;       // 6 MB
  bf16* wtout = (bf16*)ws; ws += (size_t)E * E * 2;        // 2 MB
  bf16* qB    = (bf16*)ws; ws += (size_t)B * H * S * D * 2; // 8 MB
  bf16* kB    = (bf16*)ws; ws += (size_t)B * H * S * D * 2; // 8 MB
  bf16* vT    = (bf16*)ws; ws += (size_t)B * H * S * D * 2; // 8 MB
  bf16* ao    = (bf16*)ws; ws += (size_t)M * E * 2;        // 8 MB

  k_cvt<<<M * E / 1024, 256, 0, stream>>>(x, xb);
  k_transpose_cvt<<<dim3(N3 / 32, E / 32), dim3(32, 8), 0, stream>>>(W_in, wtin, E, N3);
  k_transpose_cvt<<<dim3(E / 32, E / 32), dim3(32, 8), 0, stream>>>(W_out, wtout, E, E);
  k_gemm<0><<<dim3(N3 / 128, M / 128), 256, 0, stream>>>(xb, wtin, b_in, nullptr, qB, kB, vT, E);
  k_attn<<<dim3(S / 64, B * H), 256, 0, stream>>>(qB, kB, vT, ao, cmask);
  k_gemm<1><<<dim3(E / 128, M / 128), 256, 0, stream>>>(ao, wtout, b_out, (float*)d_out,
                                                        nullptr, nullptr, nullptr, E);
}

// Round 2
// 159.616 us; speedup vs baseline: 1.4589x; 1.4589x over previous
//
#include <hip/hip_runtime.h>
#include <hip/hip_bf16.h>
#include <cmath>

typedef __bf16 bf16;
typedef __attribute__((ext_vector_type(8))) __bf16 bf16x8;
typedef __attribute__((ext_vector_type(4))) __bf16 bf16x4;
typedef __attribute__((ext_vector_type(4))) float f32x4;

constexpr int S  = 2048;
constexpr int E  = 1024;
constexpr int H  = 16;
constexpr int D  = 64;
constexpr int B  = 2;
constexpr int M  = B * S;   // 4096 rows
constexpr int N3 = 3 * E;   // 3072

static __device__ __forceinline__ void gload16(const void* g, void* l) {
  __builtin_amdgcn_global_load_lds((const __attribute__((address_space(1))) void*)g,
                                   (__attribute__((address_space(3))) void*)l, 16, 0, 0);
}

// ---------- f32 -> bf16 elementwise (vectorized, G13) ----------
__global__ void k_cvt(const float* __restrict__ in, bf16* __restrict__ out) {
  const int i = (blockIdx.x * blockDim.x + threadIdx.x) * 4;
  const float4 v = *(const float4*)(in + i);
  bf16x4 o = { (bf16)v.x, (bf16)v.y, (bf16)v.z, (bf16)v.w };
  *(bf16x4*)(out + i) = o;
}

// ---------- f32 [R][C] -> bf16 [C][R] (LDS tile transpose) ----------
__global__ void k_transpose_cvt(const float* __restrict__ in, bf16* __restrict__ out,
                                int R, int C) {
  __shared__ float t[32][33];
  const int c0 = blockIdx.x * 32, r0 = blockIdx.y * 32;
  const int tx = threadIdx.x, ty = threadIdx.y;
  #pragma unroll
  for (int j = 0; j < 32; j += 8)
    t[ty + j][tx] = in[(size_t)(r0 + ty + j) * C + c0 + tx];
  __syncthreads();
  #pragma unroll
  for (int j = 0; j < 32; j += 8)
    out[(size_t)(c0 + ty + j) * R + r0 + tx] = (bf16)t[tx][ty + j];
}

// ---------- GEMM: C[M][N] = A[M][K](bf16) * Bt[N][K](bf16)^T + bias ----------
// (unchanged from round 1 — m97-style, passed correctness)
template<int EPI>
__global__ __launch_bounds__(256) void k_gemm(
    const bf16* __restrict__ A, const bf16* __restrict__ Bt,
    const float* __restrict__ bias, float* __restrict__ outF,
    bf16* __restrict__ oQ, bf16* __restrict__ oK, bf16* __restrict__ oV, int Kdim)
{
  __shared__ __align__(16) char lA[128 * 128];
  __shared__ __align__(16) char lB[128 * 128];
  const int tid = threadIdx.x;
  const int lane = tid & 63, w = tid >> 6;
  const int wm = w >> 1, wn = w & 1;
  const int bn0 = blockIdx.x * 128, bm0 = blockIdx.y * 128;
  f32x4 acc[4][4] = {};

  const int nkt = Kdim >> 6;
  for (int kt = 0; kt < nkt; ++kt) {
    __syncthreads();
    const int k0 = kt << 6;
    #pragma unroll
    for (int p = 0; p < 4; ++p) {
      const int o = p * 4096 + w * 1024 + lane * 16;
      const int row = o >> 7;
      const int cb = o & 127;
      const int lk = (cb ^ ((row & 7) << 4)) >> 1;
      gload16(A + (size_t)(bm0 + row) * Kdim + k0 + lk, lA + p * 4096 + w * 1024);
      gload16(Bt + (size_t)(bn0 + row) * Kdim + k0 + lk, lB + p * 4096 + w * 1024);
    }
    asm volatile("s_waitcnt vmcnt(0)" ::: "memory");
    __syncthreads();

    #pragma unroll
    for (int kk = 0; kk < 2; ++kk) {
      bf16x8 af[4], bfr[4];
      #pragma unroll
      for (int f = 0; f < 4; ++f) {
        const int ra = wm * 64 + f * 16 + (lane & 15);
        af[f] = *(const bf16x8*)(lA + ra * 128 +
                 ((kk * 64 + ((lane >> 4) << 4)) ^ ((ra & 7) << 4)));
        const int rb = wn * 64 + f * 16 + (lane & 15);
        bfr[f] = *(const bf16x8*)(lB + rb * 128 +
                 ((kk * 64 + ((lane >> 4) << 4)) ^ ((rb & 7) << 4)));
      }
      #pragma unroll
      for (int i = 0; i < 4; ++i)
        #pragma unroll
        for (int j = 0; j < 4; ++j)
          acc[i][j] = __builtin_amdgcn_mfma_f32_16x16x32_bf16(af[i], bfr[j], acc[i][j], 0, 0, 0);
    }
  }

  #pragma unroll
  for (int i = 0; i < 4; ++i) {
    #pragma unroll
    for (int j = 0; j < 4; ++j) {
      const int n = bn0 + wn * 64 + j * 16 + (lane & 15);
      const float bv = bias[n];
      #pragma unroll
      for (int r = 0; r < 4; ++r) {
        const int m = bm0 + wm * 64 + i * 16 + ((lane >> 4) << 2) + r;
        const float v = acc[i][j][r] + bv;
        if constexpr (EPI == 0) {
          const int b = m >> 11, s = m & (S - 1);
          const int which = n >> 10, c = n & (E - 1);
          const int h = c >> 6, d = c & 63;
          const size_t bh = (size_t)b * H + h;
          if (which == 0)      oQ[(bh * S + s) * D + d] = (bf16)v;
          else if (which == 1) oK[(bh * S + s) * D + d] = (bf16)v;
          else                 oV[(bh * D + d) * S + s] = (bf16)v;
        } else {
          outF[(size_t)m * E + n] = v;
        }
      }
    }
  }
}

// ---------- flash attention (causal), balanced + double-buffered ----------
// grid (bh=32, px=16), 256 thr = 4 waves. Block processes q-tiles (31-px) then
// (px): exactly 33 causal KV-tiles per block -> uniform load. K/V LDS tiles are
// double-buffered; next tile staged with global_load_lds before computing the
// current one; counted s_waitcnt vmcnt(4) + raw s_barrier (no vmcnt(0) drain).
__global__ __launch_bounds__(256) void k_attn(
    const bf16* __restrict__ Qb, const bf16* __restrict__ Kb, const bf16* __restrict__ Vt,
    bf16* __restrict__ AO, const int* __restrict__ cmask)
{
  __shared__ __align__(16) char lK[2][64 * 128];
  __shared__ __align__(16) char lV[2][64 * 128];
  __shared__ __align__(16) char lP[4][16 * 128];
  const int tid = threadIdx.x, lane = tid & 63, w = tid >> 6;
  const int bh = blockIdx.x;   // 0..31 -> XCD = bh % 8 (L2 locality per head)
  const int px = blockIdx.y;   // 0..15 pair index
  const int causal = cmask[0];
  const bf16* Qh = Qb + (size_t)bh * S * D;
  const bf16* Kh = Kb + (size_t)bh * S * D;
  const bf16* Vh = Vt + (size_t)bh * D * S;
  char* lPw = lP[w];
  const float S2 = 0.18033688011112042f;  // (1/sqrt(D)) * log2(e)

  // staging geometry (constant across tiles)
  const int so0 = w * 1024 + lane * 16;
  int srow[2], slk[2];
  #pragma unroll
  for (int p = 0; p < 2; ++p) {
    const int o = p * 4096 + so0;
    const int row = o >> 7, cb = o & 127;
    srow[p] = row;
    slk[p] = (cb ^ ((row & 7) << 4)) >> 1;
  }

  #pragma unroll 1
  for (int pass = 0; pass < 2; ++pass) {
    const int qb = pass ? px : (31 - px);
    const int q0 = qb * 64;
    const int nkt = causal ? (qb + 1) : (S / 64);
    const int qrow = q0 + w * 16 + (lane & 15);
    const int myq  = q0 + w * 16 + ((lane >> 4) << 2);

    __builtin_amdgcn_s_barrier();  // buffers free of previous pass's readers

    const bf16x8 qf0 = *(const bf16x8*)(Qh + (size_t)qrow * D + ((lane >> 4) << 3));
    const bf16x8 qf1 = *(const bf16x8*)(Qh + (size_t)qrow * D + 32 + ((lane >> 4) << 3));

    // prologue: stage tile 0 -> buf 0
    #pragma unroll
    for (int p = 0; p < 2; ++p) {
      gload16(Kh + (size_t)srow[p] * D + slk[p], lK[0] + p * 4096 + so0);
      gload16(Vh + (size_t)srow[p] * S + slk[p], lV[0] + p * 4096 + so0);
    }

    f32x4 oacc[4] = {};
    float mrow[4], lrow[4];
    #pragma unroll
    for (int i = 0; i < 4; ++i) { mrow[i] = -INFINITY; lrow[i] = 0.f; }

    #pragma unroll 1
    for (int t = 0; t < nkt; ++t) {
      const int c = t & 1;
      __builtin_amdgcn_s_barrier();  // B1: everyone done reading buf c^1
      if (t + 1 < nkt) {
        const int kb = (t + 1) * 64;
        #pragma unroll
        for (int p = 0; p < 2; ++p) {
          gload16(Kh + (size_t)(kb + srow[p]) * D + slk[p], lK[c ^ 1] + p * 4096 + so0);
          gload16(Vh + (size_t)srow[p] * S + kb + slk[p],   lV[c ^ 1] + p * 4096 + so0);
        }
        asm volatile("s_waitcnt vmcnt(4)" ::: "memory");  // tile t landed; t+1 in flight
      } else {
        asm volatile("s_waitcnt vmcnt(0)" ::: "memory");
      }
      __builtin_amdgcn_s_barrier();  // B2: tile t visible to all waves

      // QK^T: scores 16q x 64k per wave
      f32x4 sc[4] = {};
      #pragma unroll
      for (int f = 0; f < 4; ++f) {
        const int rk = f * 16 + (lane & 15);
        const int swz = (rk & 7) << 4;
        const bf16x8 kf0 = *(const bf16x8*)(lK[c] + rk * 128 + ((((lane >> 4) << 4)) ^ swz));
        const bf16x8 kf1 = *(const bf16x8*)(lK[c] + rk * 128 + ((64 + ((lane >> 4) << 4)) ^ swz));
        sc[f] = __builtin_amdgcn_mfma_f32_16x16x32_bf16(qf0, kf0, sc[f], 0, 0, 0);
        sc[f] = __builtin_amdgcn_mfma_f32_16x16x32_bf16(qf1, kf1, sc[f], 0, 0, 0);
      }

      // causal mask only on the diagonal tile (wave-uniform branch)
      if (causal && t == nkt - 1) {
        #pragma unroll
        for (int f = 0; f < 4; ++f) {
          const int kg = t * 64 + f * 16 + (lane & 15);
          #pragma unroll
          for (int i = 0; i < 4; ++i)
            if (kg > myq + i) sc[f][i] = -INFINITY;
        }
      }

      // online softmax in exp2 domain
      float tmax[4];
      #pragma unroll
      for (int i = 0; i < 4; ++i)
        tmax[i] = fmaxf(fmaxf(sc[0][i], sc[1][i]), fmaxf(sc[2][i], sc[3][i]));
      #pragma unroll
      for (int x = 1; x < 16; x <<= 1)
        #pragma unroll
        for (int i = 0; i < 4; ++i)
          tmax[i] = fmaxf(tmax[i], __shfl_xor(tmax[i], x, 64));

      float mnew[4], corr[4], msc[4];
      #pragma unroll
      for (int i = 0; i < 4; ++i) {
        mnew[i] = fmaxf(mrow[i], tmax[i]);
        corr[i] = __builtin_amdgcn_exp2f((mrow[i] - mnew[i]) * S2);  // exp2(-inf)=0 on 1st tile
        msc[i]  = mnew[i] * S2;
      }

      float psum[4] = {0.f, 0.f, 0.f, 0.f};
      #pragma unroll
      for (int f = 0; f < 4; ++f) {
        #pragma unroll
        for (int i = 0; i < 4; ++i) {
          const float p = __builtin_amdgcn_exp2f(__builtin_fmaf(sc[f][i], S2, -msc[i]));
          psum[i] += p;
          const int pr = ((lane >> 4) << 2) + i;
          const int pcb = (((lane & 15) + 16 * f) << 1) ^ ((pr & 7) << 4);
          *(bf16*)(lPw + pr * 128 + pcb) = (bf16)p;
        }
      }
      #pragma unroll
      for (int x = 1; x < 16; x <<= 1)
        #pragma unroll
        for (int i = 0; i < 4; ++i)
          psum[i] += __shfl_xor(psum[i], x, 64);

      #pragma unroll
      for (int i = 0; i < 4; ++i) {
        lrow[i] = lrow[i] * corr[i] + psum[i];
        mrow[i] = mnew[i];
      }
      #pragma unroll
      for (int fd = 0; fd < 4; ++fd)
        #pragma unroll
        for (int i = 0; i < 4; ++i)
          oacc[fd][i] *= corr[i];

      // PV: out[16q][64d] += P[16,64] @ V[64,64]
      #pragma unroll
      for (int kk = 0; kk < 2; ++kk) {
        const int pr2 = lane & 15;
        const bf16x8 pa = *(const bf16x8*)(lPw + pr2 * 128 +
                          ((kk * 64 + ((lane >> 4) << 4)) ^ ((pr2 & 7) << 4)));
        #pragma unroll
        for (int fd = 0; fd < 4; ++fd) {
          const int rv = fd * 16 + (lane & 15);
          const bf16x8 vf = *(const bf16x8*)(lV[c] + rv * 128 +
                            ((kk * 64 + ((lane >> 4) << 4)) ^ ((rv & 7) << 4)));
          oacc[fd] = __builtin_amdgcn_mfma_f32_16x16x32_bf16(pa, vf, oacc[fd], 0, 0, 0);
        }
      }
    }  // t

    // normalize + write AO[B,S,E] bf16
    const int b = bh >> 4, h = bh & 15;
    #pragma unroll
    for (int fd = 0; fd < 4; ++fd) {
      #pragma unroll
      for (int i = 0; i < 4; ++i) {
        const int qg = myq + i;
        const int d = fd * 16 + (lane & 15);
        AO[((size_t)(b * S + qg)) * E + h * D + d] = (bf16)(oacc[fd][i] / lrow[i]);
      }
    }
  }  // pass
}

extern "C" void kernel_launch(void* const* d_in, const int* in_sizes, int n_in,
                              void* d_out, int out_size, void* d_ws, size_t ws_size,
                              hipStream_t stream) {
  (void)in_sizes; (void)n_in; (void)out_size; (void)ws_size;
  const float* x     = (const float*)d_in[0];
  const float* W_in  = (const float*)d_in[1];
  const float* b_in  = (const float*)d_in[2];
  const float* W_out = (const float*)d_in[3];
  const float* b_out = (const float*)d_in[4];
  const int*   cmask = (const int*)d_in[5];

  char* ws = (char*)d_ws;
  bf16* xb    = (bf16*)ws; ws += (size_t)M * E * 2;
  bf16* wtin  = (bf16*)ws; ws += (size_t)N3 * E * 2;
  bf16* wtout = (bf16*)ws; ws += (size_t)E * E * 2;
  bf16* qB    = (bf16*)ws; ws += (size_t)B * H * S * D * 2;
  bf16* kB    = (bf16*)ws; ws += (size_t)B * H * S * D * 2;
  bf16* vT    = (bf16*)ws; ws += (size_t)B * H * S * D * 2;
  bf16* ao    = (bf16*)ws; ws += (size_t)M * E * 2;

  k_cvt<<<M * E / 1024, 256, 0, stream>>>(x, xb);
  k_transpose_cvt<<<dim3(N3 / 32, E / 32), dim3(32, 8), 0, stream>>>(W_in, wtin, E, N3);
  k_transpose_cvt<<<dim3(E / 32, E / 32), dim3(32, 8), 0, stream>>>(W_out, wtout, E, E);
  k_gemm<0><<<dim3(N3 / 128, M / 128), 256, 0, stream>>>(xb, wtin, b_in, nullptr, qB, kB, vT, E);
  k_attn<<<dim3(32, 16), 256, 0, stream>>>(qB, kB, vT, ao, cmask);
  k_gemm<1><<<dim3(E / 128, M / 128), 256, 0, stream>>>(ao, wtout, b_out, (float*)d_out,
                                                        nullptr, nullptr, nullptr, E);
}

// Round 3
// 146.967 us; speedup vs baseline: 1.5844x; 1.0861x over previous
//
#include <hip/hip_runtime.h>
#include <hip/hip_bf16.h>
#include <cmath>

typedef __bf16 bf16;
typedef __attribute__((ext_vector_type(8))) __bf16 bf16x8;
typedef __attribute__((ext_vector_type(4))) __bf16 bf16x4;
typedef __attribute__((ext_vector_type(4))) float f32x4;
typedef __attribute__((ext_vector_type(16))) float f32x16;
typedef unsigned int u32;

constexpr int S  = 2048;
constexpr int E  = 1024;
constexpr int H  = 16;
constexpr int D  = 64;
constexpr int B  = 2;
constexpr int M  = B * S;   // 4096 rows
constexpr int N3 = 3 * E;   // 3072

static __device__ __forceinline__ void gload16(const void* g, void* l) {
  __builtin_amdgcn_global_load_lds((const __attribute__((address_space(1))) void*)g,
                                   (__attribute__((address_space(3))) void*)l, 16, 0, 0);
}

static __device__ __forceinline__ u32 pack2(float a, float b) {
  union { bf16 h[2]; u32 u; } r;
  r.h[0] = (bf16)a; r.h[1] = (bf16)b;
  return r.u;
}
typedef union { u32 w[4]; bf16x8 v; } FU;

// ---------- f32 -> bf16 elementwise ----------
__global__ void k_cvt(const float* __restrict__ in, bf16* __restrict__ out) {
  const int i = (blockIdx.x * blockDim.x + threadIdx.x) * 4;
  const float4 v = *(const float4*)(in + i);
  bf16x4 o = { (bf16)v.x, (bf16)v.y, (bf16)v.z, (bf16)v.w };
  *(bf16x4*)(out + i) = o;
}

// ---------- f32 [R][C] -> bf16 [C][R] ----------
__global__ void k_transpose_cvt(const float* __restrict__ in, bf16* __restrict__ out,
                                int R, int C) {
  __shared__ float t[32][33];
  const int c0 = blockIdx.x * 32, r0 = blockIdx.y * 32;
  const int tx = threadIdx.x, ty = threadIdx.y;
  #pragma unroll
  for (int j = 0; j < 32; j += 8)
    t[ty + j][tx] = in[(size_t)(r0 + ty + j) * C + c0 + tx];
  __syncthreads();
  #pragma unroll
  for (int j = 0; j < 32; j += 8)
    out[(size_t)(c0 + ty + j) * R + r0 + tx] = (bf16)t[tx][ty + j];
}

// ---------- GEMM (unchanged from round 1/2, verified) ----------
template<int EPI>
__global__ __launch_bounds__(256) void k_gemm(
    const bf16* __restrict__ A, const bf16* __restrict__ Bt,
    const float* __restrict__ bias, float* __restrict__ outF,
    bf16* __restrict__ oQ, bf16* __restrict__ oK, bf16* __restrict__ oV, int Kdim)
{
  __shared__ __align__(16) char lA[128 * 128];
  __shared__ __align__(16) char lB[128 * 128];
  const int tid = threadIdx.x;
  const int lane = tid & 63, w = tid >> 6;
  const int wm = w >> 1, wn = w & 1;
  const int bn0 = blockIdx.x * 128, bm0 = blockIdx.y * 128;
  f32x4 acc[4][4] = {};

  const int nkt = Kdim >> 6;
  for (int kt = 0; kt < nkt; ++kt) {
    __syncthreads();
    const int k0 = kt << 6;
    #pragma unroll
    for (int p = 0; p < 4; ++p) {
      const int o = p * 4096 + w * 1024 + lane * 16;
      const int row = o >> 7;
      const int cb = o & 127;
      const int lk = (cb ^ ((row & 7) << 4)) >> 1;
      gload16(A + (size_t)(bm0 + row) * Kdim + k0 + lk, lA + p * 4096 + w * 1024);
      gload16(Bt + (size_t)(bn0 + row) * Kdim + k0 + lk, lB + p * 4096 + w * 1024);
    }
    asm volatile("s_waitcnt vmcnt(0)" ::: "memory");
    __syncthreads();

    #pragma unroll
    for (int kk = 0; kk < 2; ++kk) {
      bf16x8 af[4], bfr[4];
      #pragma unroll
      for (int f = 0; f < 4; ++f) {
        const int ra = wm * 64 + f * 16 + (lane & 15);
        af[f] = *(const bf16x8*)(lA + ra * 128 +
                 ((kk * 64 + ((lane >> 4) << 4)) ^ ((ra & 7) << 4)));
        const int rb = wn * 64 + f * 16 + (lane & 15);
        bfr[f] = *(const bf16x8*)(lB + rb * 128 +
                 ((kk * 64 + ((lane >> 4) << 4)) ^ ((rb & 7) << 4)));
      }
      #pragma unroll
      for (int i = 0; i < 4; ++i)
        #pragma unroll
        for (int j = 0; j < 4; ++j)
          acc[i][j] = __builtin_amdgcn_mfma_f32_16x16x32_bf16(af[i], bfr[j], acc[i][j], 0, 0, 0);
    }
  }

  #pragma unroll
  for (int i = 0; i < 4; ++i) {
    #pragma unroll
    for (int j = 0; j < 4; ++j) {
      const int n = bn0 + wn * 64 + j * 16 + (lane & 15);
      const float bv = bias[n];
      #pragma unroll
      for (int r = 0; r < 4; ++r) {
        const int m = bm0 + wm * 64 + i * 16 + ((lane >> 4) << 2) + r;
        const float v = acc[i][j][r] + bv;
        if constexpr (EPI == 0) {
          const int b = m >> 11, s = m & (S - 1);
          const int which = n >> 10, c = n & (E - 1);
          const int h = c >> 6, d = c & 63;
          const size_t bh = (size_t)b * H + h;
          if (which == 0)      oQ[(bh * S + s) * D + d] = (bf16)v;
          else if (which == 1) oK[(bh * S + s) * D + d] = (bf16)v;
          else                 oV[(bh * D + d) * S + s] = (bf16)v;
        } else {
          outF[(size_t)m * E + n] = v;
        }
      }
    }
  }
}

// ---------- flash attention: 32x32 swapped-QK^T, in-register softmax ----------
// grid (bh=32, 16), 256 thr = 4 waves x 32 q-rows = 128 q/block.
// c = 15 - blockIdx.y (LPT: longest chunks dispatch first).
// Swapped QK^T: sc = mfma(K, Q) -> lane holds P[q=lane&31][k=crow(r,h)+32*sub],
// crow(r,h) = (r&3)+8*(r>>2)+4*h. Row reduce = in-reg tree + shfl_xor(32).
// P -> A-fragment: pack2 pairs + v_permlane32_swap_b32 (T12 derivation in notes).
// O-rescale / final 1/l: per-wave LDS broadcast of corr/lrow (per-acc-row relayout).
__global__ __launch_bounds__(256, 2) void k_attn(
    const bf16* __restrict__ Qb, const bf16* __restrict__ Kb, const bf16* __restrict__ Vt,
    bf16* __restrict__ AO, const int* __restrict__ cmask)
{
  __shared__ __align__(16) char lK[2][64 * 128];
  __shared__ __align__(16) char lV[2][64 * 128];
  __shared__ __align__(16) float corr_lds[4][32];
  __shared__ __align__(16) float lrow_lds[4][32];

  const int tid = threadIdx.x, lane = tid & 63, w = tid >> 6;
  const int h = lane >> 5, q31 = lane & 31;
  const int bh = blockIdx.x;
  const int c  = 15 - (int)blockIdx.y;
  const int causal = cmask[0];
  const int q0w = c * 128 + 32 * w;
  const int qg  = q0w + q31;
  const int nkt   = causal ? (2 * c + 2) : (S / 64);
  const int nkt_w = causal ? (2 * c + 1 + (w >> 1)) : (S / 64);
  const float S2 = 0.18033688011112042f;  // (1/sqrt(D)) * log2(e)

  const bf16* Qh = Qb + (size_t)bh * S * D;
  const bf16* Kh = Kb + (size_t)bh * S * D;
  const bf16* Vh = Vt + (size_t)bh * D * S;

  // staging geometry (64x64 bf16 tile, 128B rows, XOR-swizzle via source)
  const int so0 = w * 1024 + lane * 16;
  int srow[2], slk[2];
  #pragma unroll
  for (int p = 0; p < 2; ++p) {
    const int o = p * 4096 + so0;
    const int row = o >> 7, cb = o & 127;
    srow[p] = row;
    slk[p] = (cb ^ ((row & 7) << 4)) >> 1;
  }

  // Q fragments (B-operand: n=lane&31=q, k=(lane>>5)*8+i), d-slices ds=0..3
  bf16x8 qf[4];
  #pragma unroll
  for (int ds = 0; ds < 4; ++ds)
    qf[ds] = *(const bf16x8*)(Qh + (size_t)qg * D + 16 * ds + 8 * h);

  // prologue: stage tile 0 -> buf 0
  #pragma unroll
  for (int p = 0; p < 2; ++p) {
    gload16(Kh + (size_t)srow[p] * D + slk[p], lK[0] + p * 4096 + so0);
    gload16(Vh + (size_t)srow[p] * S + slk[p], lV[0] + p * 4096 + so0);
  }

  f32x16 o0 = {}, o1 = {};
  float mrun = -INFINITY, lr = 0.f;
  const int swz = (q31 & 7) << 4;

  #pragma unroll 1
  for (int t = 0; t < nkt; ++t) {
    const int cb = t & 1;
    __builtin_amdgcn_s_barrier();  // buf cb^1 free of readers
    if (t + 1 < nkt) {
      const int kb = (t + 1) * 64;
      #pragma unroll
      for (int p = 0; p < 2; ++p) {
        gload16(Kh + (size_t)(kb + srow[p]) * D + slk[p], lK[cb ^ 1] + p * 4096 + so0);
        gload16(Vh + (size_t)srow[p] * S + kb + slk[p],   lV[cb ^ 1] + p * 4096 + so0);
      }
      asm volatile("s_waitcnt vmcnt(4)" ::: "memory");
    } else {
      asm volatile("s_waitcnt vmcnt(0)" ::: "memory");
    }
    __builtin_amdgcn_s_barrier();  // tile t visible

    if (t < nkt_w) {
      // QK^T swapped: sc[sub] = K[32*sub..][*] x Q -> P rows
      f32x16 s0v = {}, s1v = {};
      #pragma unroll
      for (int ds = 0; ds < 4; ++ds) {
        const int col = (32 * ds + 16 * h) ^ swz;
        const bf16x8 kf0 = *(const bf16x8*)(lK[cb] + q31 * 128 + col);
        const bf16x8 kf1 = *(const bf16x8*)(lK[cb] + (32 + q31) * 128 + col);
        s0v = __builtin_amdgcn_mfma_f32_32x32x16_bf16(kf0, qf[ds], s0v, 0, 0, 0);
        s1v = __builtin_amdgcn_mfma_f32_32x32x16_bf16(kf1, qf[ds], s1v, 0, 0, 0);
      }

      // causal mask only on the wave's last tile
      if (causal && t == nkt_w - 1) {
        #pragma unroll
        for (int r = 0; r < 16; ++r) {
          const int kg = 64 * t + (r & 3) + 8 * (r >> 2) + 4 * h;
          if (kg > qg)      s0v[r] = -INFINITY;
          if (kg + 32 > qg) s1v[r] = -INFINITY;
        }
      }

      // row max: tree + one cross-half shuffle
      float a8[8];
      #pragma unroll
      for (int i = 0; i < 8; ++i)
        a8[i] = fmaxf(fmaxf(s0v[i], s0v[i + 8]), fmaxf(s1v[i], s1v[i + 8]));
      float tmax = fmaxf(fmaxf(fmaxf(a8[0], a8[1]), fmaxf(a8[2], a8[3])),
                         fmaxf(fmaxf(a8[4], a8[5]), fmaxf(a8[6], a8[7])));
      tmax = fmaxf(tmax, __shfl_xor(tmax, 32, 64));

      const bool nogrow = __all(tmax <= mrun);   // T13: skip rescale when max doesn't grow
      const float mnew = nogrow ? mrun : fmaxf(mrun, tmax);
      float corrf = 1.f;
      if (!nogrow) {
        corrf = __builtin_amdgcn_exp2f((mrun - mnew) * S2);
        corr_lds[w][q31] = corrf;
      }
      const float msc = mnew * S2;

      #pragma unroll
      for (int r = 0; r < 16; ++r) {
        s0v[r] = __builtin_amdgcn_exp2f(__builtin_fmaf(s0v[r], S2, -msc));
        s1v[r] = __builtin_amdgcn_exp2f(__builtin_fmaf(s1v[r], S2, -msc));
      }

      float b8[8];
      #pragma unroll
      for (int i = 0; i < 8; ++i)
        b8[i] = (s0v[i] + s0v[i + 8]) + (s1v[i] + s1v[i + 8]);
      float psum = ((b8[0] + b8[1]) + (b8[2] + b8[3])) + ((b8[4] + b8[5]) + (b8[6] + b8[7]));
      psum += __shfl_xor(psum, 32, 64);
      lr = lr * corrf + psum;
      mrun = mnew;

      // pack P pairs: pk[block jj][word]; block jj covers k = 8*jj + 4h .. +3
      u32 pk[8][2];
      #pragma unroll
      for (int jj = 0; jj < 4; ++jj) {
        pk[jj][0]     = pack2(s0v[4 * jj],     s0v[4 * jj + 1]);
        pk[jj][1]     = pack2(s0v[4 * jj + 2], s0v[4 * jj + 3]);
        pk[jj + 4][0] = pack2(s1v[4 * jj],     s1v[4 * jj + 1]);
        pk[jj + 4][1] = pack2(s1v[4 * jj + 2], s1v[4 * jj + 3]);
      }

      // O rescale with per-acc-row corr (LDS broadcast read, conflict-free)
      if (!nogrow) {
        #pragma unroll
        for (int j = 0; j < 4; ++j) {
          const f32x4 cv = *(const f32x4*)&corr_lds[w][8 * j + 4 * h];
          #pragma unroll
          for (int sr = 0; sr < 4; ++sr) {
            o0[4 * j + sr] *= cv[sr];
            o1[4 * j + sr] *= cv[sr];
          }
        }
      }

      // PV: per k-slice ks, build A-fragment via 2 permlane swaps, 2 mfma (d-tiles)
      #pragma unroll
      for (int ks = 0; ks < 4; ++ks) {
        u32 a0 = pk[2 * ks][0], b0 = pk[2 * ks + 1][0];
        u32 a1 = pk[2 * ks][1], b1 = pk[2 * ks + 1][1];
        asm volatile("v_permlane32_swap_b32 %0, %1" : "+v"(a0), "+v"(b0));
        asm volatile("v_permlane32_swap_b32 %0, %1" : "+v"(a1), "+v"(b1));
        FU f; f.w[0] = a0; f.w[1] = a1; f.w[2] = b0; f.w[3] = b1;
        const int col = (32 * ks + 16 * h) ^ swz;
        const bf16x8 vf0 = *(const bf16x8*)(lV[cb] + q31 * 128 + col);
        const bf16x8 vf1 = *(const bf16x8*)(lV[cb] + (32 + q31) * 128 + col);
        o0 = __builtin_amdgcn_mfma_f32_32x32x16_bf16(f.v, vf0, o0, 0, 0, 0);
        o1 = __builtin_amdgcn_mfma_f32_32x32x16_bf16(f.v, vf1, o1, 0, 0, 0);
      }
    }
  }

  // epilogue: normalize with per-acc-row lrow (LDS broadcast), write AO[B,S,E]
  lrow_lds[w][q31] = lr;
  const int b = bh >> 4, h16 = bh & 15;
  #pragma unroll
  for (int j = 0; j < 4; ++j) {
    const f32x4 lv = *(const f32x4*)&lrow_lds[w][8 * j + 4 * h];
    #pragma unroll
    for (int sr = 0; sr < 4; ++sr) {
      const int r = 4 * j + sr;
      const float inv = 1.0f / lv[sr];
      const int qrow = q0w + (r & 3) + 8 * (r >> 2) + 4 * h;
      bf16* dst = AO + ((size_t)(b * S + qrow)) * E + h16 * D;
      dst[q31]      = (bf16)(o0[r] * inv);
      dst[32 + q31] = (bf16)(o1[r] * inv);
    }
  }
}

extern "C" void kernel_launch(void* const* d_in, const int* in_sizes, int n_in,
                              void* d_out, int out_size, void* d_ws, size_t ws_size,
                              hipStream_t stream) {
  (void)in_sizes; (void)n_in; (void)out_size; (void)ws_size;
  const float* x     = (const float*)d_in[0];
  const float* W_in  = (const float*)d_in[1];
  const float* b_in  = (const float*)d_in[2];
  const float* W_out = (const float*)d_in[3];
  const float* b_out = (const float*)d_in[4];
  const int*   cmask = (const int*)d_in[5];

  char* ws = (char*)d_ws;
  bf16* xb    = (bf16*)ws; ws += (size_t)M * E * 2;
  bf16* wtin  = (bf16*)ws; ws += (size_t)N3 * E * 2;
  bf16* wtout = (bf16*)ws; ws += (size_t)E * E * 2;
  bf16* qB    = (bf16*)ws; ws += (size_t)B * H * S * D * 2;
  bf16* kB    = (bf16*)ws; ws += (size_t)B * H * S * D * 2;
  bf16* vT    = (bf16*)ws; ws += (size_t)B * H * S * D * 2;
  bf16* ao    = (bf16*)ws; ws += (size_t)M * E * 2;

  k_cvt<<<M * E / 1024, 256, 0, stream>>>(x, xb);
  k_transpose_cvt<<<dim3(N3 / 32, E / 32), dim3(32, 8), 0, stream>>>(W_in, wtin, E, N3);
  k_transpose_cvt<<<dim3(E / 32, E / 32), dim3(32, 8), 0, stream>>>(W_out, wtout, E, E);
  k_gemm<0><<<dim3(N3 / 128, M / 128), 256, 0, stream>>>(xb, wtin, b_in, nullptr, qB, kB, vT, E);
  k_attn<<<dim3(32, 16), 256, 0, stream>>>(qB, kB, vT, ao, cmask);
  k_gemm<1><<<dim3(E / 128, M / 128), 256, 0, stream>>>(ao, wtout, b_out, (float*)d_out,
                                                        nullptr, nullptr, nullptr, E);
}

// Round 4
// 120.869 us; speedup vs baseline: 1.9266x; 1.2159x over previous
//
#include <hip/hip_runtime.h>
#include <hip/hip_bf16.h>
#include <cmath>

typedef __bf16 bf16;
typedef __attribute__((ext_vector_type(8))) __bf16 bf16x8;
typedef __attribute__((ext_vector_type(4))) __bf16 bf16x4;
typedef __attribute__((ext_vector_type(4))) float f32x4;
typedef __attribute__((ext_vector_type(16))) float f32x16;
typedef unsigned int u32;

constexpr int S  = 2048;
constexpr int E  = 1024;
constexpr int H  = 16;
constexpr int D  = 64;
constexpr int B  = 2;
constexpr int M  = B * S;   // 4096 rows
constexpr int N3 = 3 * E;   // 3072

static __device__ __forceinline__ void gload16(const void* g, void* l) {
  __builtin_amdgcn_global_load_lds((const __attribute__((address_space(1))) void*)g,
                                   (__attribute__((address_space(3))) void*)l, 16, 0, 0);
}

static __device__ __forceinline__ u32 pack2(float a, float b) {
  union { bf16 h[2]; u32 u; } r;
  r.h[0] = (bf16)a; r.h[1] = (bf16)b;
  return r.u;
}
typedef union { u32 w[4]; bf16x8 v; } FU;

// ---------- f32 -> bf16 elementwise ----------
__global__ void k_cvt(const float* __restrict__ in, bf16* __restrict__ out) {
  const int i = (blockIdx.x * blockDim.x + threadIdx.x) * 4;
  const float4 v = *(const float4*)(in + i);
  bf16x4 o = { (bf16)v.x, (bf16)v.y, (bf16)v.z, (bf16)v.w };
  *(bf16x4*)(out + i) = o;
}

// ---------- f32 [R][C] -> bf16 [C][R] ----------
__global__ void k_transpose_cvt(const float* __restrict__ in, bf16* __restrict__ out,
                                int R, int C) {
  __shared__ float t[32][33];
  const int c0 = blockIdx.x * 32, r0 = blockIdx.y * 32;
  const int tx = threadIdx.x, ty = threadIdx.y;
  #pragma unroll
  for (int j = 0; j < 32; j += 8)
    t[ty + j][tx] = in[(size_t)(r0 + ty + j) * C + c0 + tx];
  __syncthreads();
  #pragma unroll
  for (int j = 0; j < 32; j += 8)
    out[(size_t)(c0 + ty + j) * R + r0 + tx] = (bf16)t[tx][ty + j];
}

// ---------- GEMM: C[M][N] = A[M][K] * Bt[N][K]^T + bias ----------
// 128x128 tile, BK=64, 4 waves, DOUBLE-BUFFERED LDS + counted vmcnt(8),
// XCD-swizzled linear block id. EPI==0: Q/K via LDS-staged coalesced stores,
// V^T via register-packed bf16x4 stores. EPI==1: direct f32.
template<int EPI>
__global__ __launch_bounds__(256) void k_gemm(
    const bf16* __restrict__ A, const bf16* __restrict__ Bt,
    const float* __restrict__ bias, float* __restrict__ outF,
    bf16* __restrict__ oQ, bf16* __restrict__ oK, bf16* __restrict__ oV,
    int Kdim, int Nn)
{
  __shared__ __align__(16) char smem[65536];  // [A0|A1|B0|B1] 16KB each
  const int tid = threadIdx.x;
  const int lane = tid & 63, w = tid >> 6;
  const int lane15 = lane & 15, quad = lane >> 4;
  const int wm = w >> 1, wn = w & 1;

  const int nbx = Nn >> 7;
  const int nwg = gridDim.x;
  const int bid = blockIdx.x;
  const int swz = (bid & 7) * (nwg >> 3) + (bid >> 3);   // nwg % 8 == 0 (bijective)
  const int bn0 = (swz % nbx) * 128;
  const int bm0 = (swz / nbx) * 128;

  // staging geometry (row/col of this lane's 16B within the 128x128B tile)
  const int so0 = w * 1024 + lane * 16;
  int srow[4], slk[4];
  #pragma unroll
  for (int p = 0; p < 4; ++p) {
    const int o = p * 4096 + so0;
    const int row = o >> 7, cbyte = o & 127;
    srow[p] = row;
    slk[p] = (cbyte ^ ((row & 7) << 4)) >> 1;   // inverse-swizzled source col (elems)
  }

  f32x4 acc[4][4] = {};
  const int nkt = Kdim >> 6;

  // prologue: stage kt=0 -> buf0
  #pragma unroll
  for (int p = 0; p < 4; ++p) {
    gload16(A  + (size_t)(bm0 + srow[p]) * Kdim + slk[p], smem +         p * 4096 + w * 1024);
    gload16(Bt + (size_t)(bn0 + srow[p]) * Kdim + slk[p], smem + 32768 + p * 4096 + w * 1024);
  }

  #pragma unroll 1
  for (int kt = 0; kt < nkt; ++kt) {
    const int cur = kt & 1;
    __builtin_amdgcn_s_barrier();                 // B1: buf cur^1 free of readers
    if (kt + 1 < nkt) {
      const int k0 = (kt + 1) << 6;
      const int nb = (cur ^ 1) * 16384;
      #pragma unroll
      for (int p = 0; p < 4; ++p) {
        gload16(A  + (size_t)(bm0 + srow[p]) * Kdim + k0 + slk[p],
                smem + nb +         p * 4096 + w * 1024);
        gload16(Bt + (size_t)(bn0 + srow[p]) * Kdim + k0 + slk[p],
                smem + nb + 32768 + p * 4096 + w * 1024);
      }
      asm volatile("s_waitcnt vmcnt(8)" ::: "memory");  // tile kt landed; kt+1 in flight
    } else {
      asm volatile("s_waitcnt vmcnt(0)" ::: "memory");
    }
    __builtin_amdgcn_s_barrier();                 // B2: tile kt visible to all waves

    const char* cA = smem + cur * 16384;
    const char* cB = smem + 32768 + cur * 16384;
    #pragma unroll
    for (int kk = 0; kk < 2; ++kk) {
      bf16x8 af[4], bfr[4];
      #pragma unroll
      for (int f = 0; f < 4; ++f) {
        const int ra = wm * 64 + f * 16 + lane15;
        af[f] = *(const bf16x8*)(cA + ra * 128 +
                 ((kk * 64 + (quad << 4)) ^ ((ra & 7) << 4)));
        const int rb = wn * 64 + f * 16 + lane15;
        bfr[f] = *(const bf16x8*)(cB + rb * 128 +
                 ((kk * 64 + (quad << 4)) ^ ((rb & 7) << 4)));
      }
      #pragma unroll
      for (int i = 0; i < 4; ++i)
        #pragma unroll
        for (int j = 0; j < 4; ++j)
          acc[i][j] = __builtin_amdgcn_mfma_f32_16x16x32_bf16(af[i], bfr[j], acc[i][j], 0, 0, 0);
    }
  }

  if constexpr (EPI == 1) {
    // direct f32 [M][E] (quarter-wave 64B-coalesced)
    #pragma unroll
    for (int i = 0; i < 4; ++i)
      #pragma unroll
      for (int j = 0; j < 4; ++j) {
        const int n = bn0 + wn * 64 + j * 16 + lane15;
        const float bv = bias[n];
        #pragma unroll
        for (int r = 0; r < 4; ++r) {
          const int m = bm0 + wm * 64 + i * 16 + quad * 4 + r;
          outF[(size_t)m * E + n] = acc[i][j][r] + bv;
        }
      }
  } else {
    const int which = bn0 >> 10;        // block-uniform: 0=Q 1=K 2=V
    const int b  = bm0 >> 11;
    const int s0 = bm0 & (S - 1);
    const int cn0 = bn0 & (E - 1);
    if (which < 2) {
      // Q/K: stage 128x128 bf16 tile in swizzled LDS, write coalesced 16B runs
      bf16* dst = (which == 0) ? oQ : oK;
      __builtin_amdgcn_s_barrier();     // all compute reads of smem done
      char* lC = smem;                  // 128 rows x 256B = 32KB
      #pragma unroll
      for (int j = 0; j < 4; ++j) {
        const int n_loc = wn * 64 + j * 16 + lane15;
        const float bv = bias[bn0 + n_loc];
        #pragma unroll
        for (int i = 0; i < 4; ++i)
          #pragma unroll
          for (int r = 0; r < 4; ++r) {
            const int m_loc = wm * 64 + i * 16 + quad * 4 + r;
            *(bf16*)(lC + m_loc * 256 + ((n_loc * 2) ^ ((m_loc & 7) << 4))) =
                (bf16)(acc[i][j][r] + bv);
          }
      }
      __builtin_amdgcn_s_barrier();
      const int h0 = cn0 >> 6;
      #pragma unroll
      for (int it = 0; it < 8; ++it) {
        const int cch = w * 64 + it * 8 + (lane >> 3);  // chunk: 128B = (m_loc, head-half)
        const int m_loc = cch >> 1, hh = cch & 1, piece = lane & 7;
        const bf16x8 vv = *(const bf16x8*)(lC + m_loc * 256 +
                          ((hh * 128 + piece * 16) ^ ((m_loc & 7) << 4)));
        *(bf16x8*)(dst + ((size_t)(b * H + h0 + hh) * S + s0 + m_loc) * D + piece * 8) = vv;
      }
    } else {
      // V^T: per (i,j) the 4 r-values are 4 consecutive s at fixed d -> bf16x4 store
      #pragma unroll
      for (int j = 0; j < 4; ++j) {
        const int n_loc = wn * 64 + j * 16 + lane15;
        const int cn = cn0 + n_loc;
        const int h = cn >> 6, d = cn & 63;
        const float bv = bias[bn0 + n_loc];
        bf16* base = oV + ((size_t)(b * H + h) * D + d) * S + s0 + wm * 64;
        #pragma unroll
        for (int i = 0; i < 4; ++i) {
          bf16x4 pk = { (bf16)(acc[i][j][0] + bv), (bf16)(acc[i][j][1] + bv),
                        (bf16)(acc[i][j][2] + bv), (bf16)(acc[i][j][3] + bv) };
          *(bf16x4*)(base + i * 16 + quad * 4) = pk;
        }
      }
    }
  }
}

// ---------- flash attention (unchanged from round 3, verified) ----------
__global__ __launch_bounds__(256, 2) void k_attn(
    const bf16* __restrict__ Qb, const bf16* __restrict__ Kb, const bf16* __restrict__ Vt,
    bf16* __restrict__ AO, const int* __restrict__ cmask)
{
  __shared__ __align__(16) char lK[2][64 * 128];
  __shared__ __align__(16) char lV[2][64 * 128];
  __shared__ __align__(16) float corr_lds[4][32];
  __shared__ __align__(16) float lrow_lds[4][32];

  const int tid = threadIdx.x, lane = tid & 63, w = tid >> 6;
  const int h = lane >> 5, q31 = lane & 31;
  const int bh = blockIdx.x;
  const int c  = 15 - (int)blockIdx.y;
  const int causal = cmask[0];
  const int q0w = c * 128 + 32 * w;
  const int qg  = q0w + q31;
  const int nkt   = causal ? (2 * c + 2) : (S / 64);
  const int nkt_w = causal ? (2 * c + 1 + (w >> 1)) : (S / 64);
  const float S2 = 0.18033688011112042f;  // (1/sqrt(D)) * log2(e)

  const bf16* Qh = Qb + (size_t)bh * S * D;
  const bf16* Kh = Kb + (size_t)bh * S * D;
  const bf16* Vh = Vt + (size_t)bh * D * S;

  const int so0 = w * 1024 + lane * 16;
  int srow[2], slk[2];
  #pragma unroll
  for (int p = 0; p < 2; ++p) {
    const int o = p * 4096 + so0;
    const int row = o >> 7, cb = o & 127;
    srow[p] = row;
    slk[p] = (cb ^ ((row & 7) << 4)) >> 1;
  }

  bf16x8 qf[4];
  #pragma unroll
  for (int ds = 0; ds < 4; ++ds)
    qf[ds] = *(const bf16x8*)(Qh + (size_t)qg * D + 16 * ds + 8 * h);

  #pragma unroll
  for (int p = 0; p < 2; ++p) {
    gload16(Kh + (size_t)srow[p] * D + slk[p], lK[0] + p * 4096 + so0);
    gload16(Vh + (size_t)srow[p] * S + slk[p], lV[0] + p * 4096 + so0);
  }

  f32x16 o0 = {}, o1 = {};
  float mrun = -INFINITY, lr = 0.f;
  const int swz = (q31 & 7) << 4;

  #pragma unroll 1
  for (int t = 0; t < nkt; ++t) {
    const int cb = t & 1;
    __builtin_amdgcn_s_barrier();
    if (t + 1 < nkt) {
      const int kb = (t + 1) * 64;
      #pragma unroll
      for (int p = 0; p < 2; ++p) {
        gload16(Kh + (size_t)(kb + srow[p]) * D + slk[p], lK[cb ^ 1] + p * 4096 + so0);
        gload16(Vh + (size_t)srow[p] * S + kb + slk[p],   lV[cb ^ 1] + p * 4096 + so0);
      }
      asm volatile("s_waitcnt vmcnt(4)" ::: "memory");
    } else {
      asm volatile("s_waitcnt vmcnt(0)" ::: "memory");
    }
    __builtin_amdgcn_s_barrier();

    if (t < nkt_w) {
      f32x16 s0v = {}, s1v = {};
      #pragma unroll
      for (int ds = 0; ds < 4; ++ds) {
        const int col = (32 * ds + 16 * h) ^ swz;
        const bf16x8 kf0 = *(const bf16x8*)(lK[cb] + q31 * 128 + col);
        const bf16x8 kf1 = *(const bf16x8*)(lK[cb] + (32 + q31) * 128 + col);
        s0v = __builtin_amdgcn_mfma_f32_32x32x16_bf16(kf0, qf[ds], s0v, 0, 0, 0);
        s1v = __builtin_amdgcn_mfma_f32_32x32x16_bf16(kf1, qf[ds], s1v, 0, 0, 0);
      }

      if (causal && t == nkt_w - 1) {
        #pragma unroll
        for (int r = 0; r < 16; ++r) {
          const int kg = 64 * t + (r & 3) + 8 * (r >> 2) + 4 * h;
          if (kg > qg)      s0v[r] = -INFINITY;
          if (kg + 32 > qg) s1v[r] = -INFINITY;
        }
      }

      float a8[8];
      #pragma unroll
      for (int i = 0; i < 8; ++i)
        a8[i] = fmaxf(fmaxf(s0v[i], s0v[i + 8]), fmaxf(s1v[i], s1v[i + 8]));
      float tmax = fmaxf(fmaxf(fmaxf(a8[0], a8[1]), fmaxf(a8[2], a8[3])),
                         fmaxf(fmaxf(a8[4], a8[5]), fmaxf(a8[6], a8[7])));
      tmax = fmaxf(tmax, __shfl_xor(tmax, 32, 64));

      const bool nogrow = __all(tmax <= mrun);
      const float mnew = nogrow ? mrun : fmaxf(mrun, tmax);
      float corrf = 1.f;
      if (!nogrow) {
        corrf = __builtin_amdgcn_exp2f((mrun - mnew) * S2);
        corr_lds[w][q31] = corrf;
      }
      const float msc = mnew * S2;

      #pragma unroll
      for (int r = 0; r < 16; ++r) {
        s0v[r] = __builtin_amdgcn_exp2f(__builtin_fmaf(s0v[r], S2, -msc));
        s1v[r] = __builtin_amdgcn_exp2f(__builtin_fmaf(s1v[r], S2, -msc));
      }

      float b8[8];
      #pragma unroll
      for (int i = 0; i < 8; ++i)
        b8[i] = (s0v[i] + s0v[i + 8]) + (s1v[i] + s1v[i + 8]);
      float psum = ((b8[0] + b8[1]) + (b8[2] + b8[3])) + ((b8[4] + b8[5]) + (b8[6] + b8[7]));
      psum += __shfl_xor(psum, 32, 64);
      lr = lr * corrf + psum;
      mrun = mnew;

      u32 pk[8][2];
      #pragma unroll
      for (int jj = 0; jj < 4; ++jj) {
        pk[jj][0]     = pack2(s0v[4 * jj],     s0v[4 * jj + 1]);
        pk[jj][1]     = pack2(s0v[4 * jj + 2], s0v[4 * jj + 3]);
        pk[jj + 4][0] = pack2(s1v[4 * jj],     s1v[4 * jj + 1]);
        pk[jj + 4][1] = pack2(s1v[4 * jj + 2], s1v[4 * jj + 3]);
      }

      if (!nogrow) {
        #pragma unroll
        for (int j = 0; j < 4; ++j) {
          const f32x4 cv = *(const f32x4*)&corr_lds[w][8 * j + 4 * h];
          #pragma unroll
          for (int sr = 0; sr < 4; ++sr) {
            o0[4 * j + sr] *= cv[sr];
            o1[4 * j + sr] *= cv[sr];
          }
        }
      }

      #pragma unroll
      for (int ks = 0; ks < 4; ++ks) {
        u32 a0 = pk[2 * ks][0], b0 = pk[2 * ks + 1][0];
        u32 a1 = pk[2 * ks][1], b1 = pk[2 * ks + 1][1];
        asm volatile("v_permlane32_swap_b32 %0, %1" : "+v"(a0), "+v"(b0));
        asm volatile("v_permlane32_swap_b32 %0, %1" : "+v"(a1), "+v"(b1));
        FU f; f.w[0] = a0; f.w[1] = a1; f.w[2] = b0; f.w[3] = b1;
        const int col = (32 * ks + 16 * h) ^ swz;
        const bf16x8 vf0 = *(const bf16x8*)(lV[cb] + q31 * 128 + col);
        const bf16x8 vf1 = *(const bf16x8*)(lV[cb] + (32 + q31) * 128 + col);
        o0 = __builtin_amdgcn_mfma_f32_32x32x16_bf16(f.v, vf0, o0, 0, 0, 0);
        o1 = __builtin_amdgcn_mfma_f32_32x32x16_bf16(f.v, vf1, o1, 0, 0, 0);
      }
    }
  }

  lrow_lds[w][q31] = lr;
  const int b = bh >> 4, h16 = bh & 15;
  #pragma unroll
  for (int j = 0; j < 4; ++j) {
    const f32x4 lv = *(const f32x4*)&lrow_lds[w][8 * j + 4 * h];
    #pragma unroll
    for (int sr = 0; sr < 4; ++sr) {
      const int r = 4 * j + sr;
      const float inv = 1.0f / lv[sr];
      const int qrow = q0w + (r & 3) + 8 * (r >> 2) + 4 * h;
      bf16* dst = AO + ((size_t)(b * S + qrow)) * E + h16 * D;
      dst[q31]      = (bf16)(o0[r] * inv);
      dst[32 + q31] = (bf16)(o1[r] * inv);
    }
  }
}

extern "C" void kernel_launch(void* const* d_in, const int* in_sizes, int n_in,
                              void* d_out, int out_size, void* d_ws, size_t ws_size,
                              hipStream_t stream) {
  (void)in_sizes; (void)n_in; (void)out_size; (void)ws_size;
  const float* x     = (const float*)d_in[0];
  const float* W_in  = (const float*)d_in[1];
  const float* b_in  = (const float*)d_in[2];
  const float* W_out = (const float*)d_in[3];
  const float* b_out = (const float*)d_in[4];
  const int*   cmask = (const int*)d_in[5];

  char* ws = (char*)d_ws;
  bf16* xb    = (bf16*)ws; ws += (size_t)M * E * 2;
  bf16* wtin  = (bf16*)ws; ws += (size_t)N3 * E * 2;
  bf16* wtout = (bf16*)ws; ws += (size_t)E * E * 2;
  bf16* qB    = (bf16*)ws; ws += (size_t)B * H * S * D * 2;
  bf16* kB    = (bf16*)ws; ws += (size_t)B * H * S * D * 2;
  bf16* vT    = (bf16*)ws; ws += (size_t)B * H * S * D * 2;
  bf16* ao    = (bf16*)ws; ws += (size_t)M * E * 2;

  k_cvt<<<M * E / 1024, 256, 0, stream>>>(x, xb);
  k_transpose_cvt<<<dim3(N3 / 32, E / 32), dim3(32, 8), 0, stream>>>(W_in, wtin, E, N3);
  k_transpose_cvt<<<dim3(E / 32, E / 32), dim3(32, 8), 0, stream>>>(W_out, wtout, E, E);
  k_gemm<0><<<dim3((M / 128) * (N3 / 128)), 256, 0, stream>>>(
      xb, wtin, b_in, nullptr, qB, kB, vT, E, N3);
  k_attn<<<dim3(32, 16), 256, 0, stream>>>(qB, kB, vT, ao, cmask);
  k_gemm<1><<<dim3((M / 128) * (E / 128)), 256, 0, stream>>>(
      ao, wtout, b_out, (float*)d_out, nullptr, nullptr, nullptr, E, E);
}

// Round 5
// 115.005 us; speedup vs baseline: 2.0248x; 1.0510x over previous
//
#include <hip/hip_runtime.h>
#include <hip/hip_bf16.h>
#include <cmath>

typedef __bf16 bf16;
typedef __attribute__((ext_vector_type(8))) __bf16 bf16x8;
typedef __attribute__((ext_vector_type(4))) __bf16 bf16x4;
typedef __attribute__((ext_vector_type(4))) float f32x4;
typedef __attribute__((ext_vector_type(16))) float f32x16;
typedef unsigned int u32;

constexpr int S  = 2048;
constexpr int E  = 1024;
constexpr int H  = 16;
constexpr int D  = 64;
constexpr int B  = 2;
constexpr int M  = B * S;       // 4096 rows
constexpr int N3 = 3 * E;       // 3072
constexpr int NROWS = B * H * S; // 65536 (q rows across batch*heads)

static __device__ __forceinline__ void gload16(const void* g, void* l) {
  __builtin_amdgcn_global_load_lds((const __attribute__((address_space(1))) void*)g,
                                   (__attribute__((address_space(3))) void*)l, 16, 0, 0);
}

static __device__ __forceinline__ u32 pack2(float a, float b) {
  union { bf16 h[2]; u32 u; } r;
  r.h[0] = (bf16)a; r.h[1] = (bf16)b;
  return r.u;
}
typedef union { u32 w[4]; bf16x8 v; } FU;

// ---------- f32 -> bf16 elementwise ----------
__global__ void k_cvt(const float* __restrict__ in, bf16* __restrict__ out) {
  const int i = (blockIdx.x * blockDim.x + threadIdx.x) * 4;
  const float4 v = *(const float4*)(in + i);
  bf16x4 o = { (bf16)v.x, (bf16)v.y, (bf16)v.z, (bf16)v.w };
  *(bf16x4*)(out + i) = o;
}

// ---------- f32 [R][C] -> bf16 [C][R] ----------
__global__ void k_transpose_cvt(const float* __restrict__ in, bf16* __restrict__ out,
                                int R, int C) {
  __shared__ float t[32][33];
  const int c0 = blockIdx.x * 32, r0 = blockIdx.y * 32;
  const int tx = threadIdx.x, ty = threadIdx.y;
  #pragma unroll
  for (int j = 0; j < 32; j += 8)
    t[ty + j][tx] = in[(size_t)(r0 + ty + j) * C + c0 + tx];
  __syncthreads();
  #pragma unroll
  for (int j = 0; j < 32; j += 8)
    out[(size_t)(c0 + ty + j) * R + r0 + tx] = (bf16)t[tx][ty + j];
}

// ---------- GEMM (unchanged from round 4, verified) ----------
template<int EPI>
__global__ __launch_bounds__(256) void k_gemm(
    const bf16* __restrict__ A, const bf16* __restrict__ Bt,
    const float* __restrict__ bias, float* __restrict__ outF,
    bf16* __restrict__ oQ, bf16* __restrict__ oK, bf16* __restrict__ oV,
    int Kdim, int Nn)
{
  __shared__ __align__(16) char smem[65536];
  const int tid = threadIdx.x;
  const int lane = tid & 63, w = tid >> 6;
  const int lane15 = lane & 15, quad = lane >> 4;
  const int wm = w >> 1, wn = w & 1;

  const int nbx = Nn >> 7;
  const int nwg = gridDim.x;
  const int bid = blockIdx.x;
  const int swz = (bid & 7) * (nwg >> 3) + (bid >> 3);
  const int bn0 = (swz % nbx) * 128;
  const int bm0 = (swz / nbx) * 128;

  const int so0 = w * 1024 + lane * 16;
  int srow[4], slk[4];
  #pragma unroll
  for (int p = 0; p < 4; ++p) {
    const int o = p * 4096 + so0;
    const int row = o >> 7, cbyte = o & 127;
    srow[p] = row;
    slk[p] = (cbyte ^ ((row & 7) << 4)) >> 1;
  }

  f32x4 acc[4][4] = {};
  const int nkt = Kdim >> 6;

  #pragma unroll
  for (int p = 0; p < 4; ++p) {
    gload16(A  + (size_t)(bm0 + srow[p]) * Kdim + slk[p], smem +         p * 4096 + w * 1024);
    gload16(Bt + (size_t)(bn0 + srow[p]) * Kdim + slk[p], smem + 32768 + p * 4096 + w * 1024);
  }

  #pragma unroll 1
  for (int kt = 0; kt < nkt; ++kt) {
    const int cur = kt & 1;
    __builtin_amdgcn_s_barrier();
    if (kt + 1 < nkt) {
      const int k0 = (kt + 1) << 6;
      const int nb = (cur ^ 1) * 16384;
      #pragma unroll
      for (int p = 0; p < 4; ++p) {
        gload16(A  + (size_t)(bm0 + srow[p]) * Kdim + k0 + slk[p],
                smem + nb +         p * 4096 + w * 1024);
        gload16(Bt + (size_t)(bn0 + srow[p]) * Kdim + k0 + slk[p],
                smem + nb + 32768 + p * 4096 + w * 1024);
      }
      asm volatile("s_waitcnt vmcnt(8)" ::: "memory");
    } else {
      asm volatile("s_waitcnt vmcnt(0)" ::: "memory");
    }
    __builtin_amdgcn_s_barrier();

    const char* cA = smem + cur * 16384;
    const char* cB = smem + 32768 + cur * 16384;
    #pragma unroll
    for (int kk = 0; kk < 2; ++kk) {
      bf16x8 af[4], bfr[4];
      #pragma unroll
      for (int f = 0; f < 4; ++f) {
        const int ra = wm * 64 + f * 16 + lane15;
        af[f] = *(const bf16x8*)(cA + ra * 128 +
                 ((kk * 64 + (quad << 4)) ^ ((ra & 7) << 4)));
        const int rb = wn * 64 + f * 16 + lane15;
        bfr[f] = *(const bf16x8*)(cB + rb * 128 +
                 ((kk * 64 + (quad << 4)) ^ ((rb & 7) << 4)));
      }
      #pragma unroll
      for (int i = 0; i < 4; ++i)
        #pragma unroll
        for (int j = 0; j < 4; ++j)
          acc[i][j] = __builtin_amdgcn_mfma_f32_16x16x32_bf16(af[i], bfr[j], acc[i][j], 0, 0, 0);
    }
  }

  if constexpr (EPI == 1) {
    #pragma unroll
    for (int i = 0; i < 4; ++i)
      #pragma unroll
      for (int j = 0; j < 4; ++j) {
        const int n = bn0 + wn * 64 + j * 16 + lane15;
        const float bv = bias[n];
        #pragma unroll
        for (int r = 0; r < 4; ++r) {
          const int m = bm0 + wm * 64 + i * 16 + quad * 4 + r;
          outF[(size_t)m * E + n] = acc[i][j][r] + bv;
        }
      }
  } else {
    const int which = bn0 >> 10;
    const int b  = bm0 >> 11;
    const int s0 = bm0 & (S - 1);
    const int cn0 = bn0 & (E - 1);
    if (which < 2) {
      bf16* dst = (which == 0) ? oQ : oK;
      __builtin_amdgcn_s_barrier();
      char* lC = smem;
      #pragma unroll
      for (int j = 0; j < 4; ++j) {
        const int n_loc = wn * 64 + j * 16 + lane15;
        const float bv = bias[bn0 + n_loc];
        #pragma unroll
        for (int i = 0; i < 4; ++i)
          #pragma unroll
          for (int r = 0; r < 4; ++r) {
            const int m_loc = wm * 64 + i * 16 + quad * 4 + r;
            *(bf16*)(lC + m_loc * 256 + ((n_loc * 2) ^ ((m_loc & 7) << 4))) =
                (bf16)(acc[i][j][r] + bv);
          }
      }
      __builtin_amdgcn_s_barrier();
      const int h0 = cn0 >> 6;
      #pragma unroll
      for (int it = 0; it < 8; ++it) {
        const int cch = w * 64 + it * 8 + (lane >> 3);
        const int m_loc = cch >> 1, hh = cch & 1, piece = lane & 7;
        const bf16x8 vv = *(const bf16x8*)(lC + m_loc * 256 +
                          ((hh * 128 + piece * 16) ^ ((m_loc & 7) << 4)));
        *(bf16x8*)(dst + ((size_t)(b * H + h0 + hh) * S + s0 + m_loc) * D + piece * 8) = vv;
      }
    } else {
      #pragma unroll
      for (int j = 0; j < 4; ++j) {
        const int n_loc = wn * 64 + j * 16 + lane15;
        const int cn = cn0 + n_loc;
        const int h = cn >> 6, d = cn & 63;
        const float bv = bias[bn0 + n_loc];
        bf16* base = oV + ((size_t)(b * H + h) * D + d) * S + s0 + wm * 64;
        #pragma unroll
        for (int i = 0; i < 4; ++i) {
          bf16x4 pk = { (bf16)(acc[i][j][0] + bv), (bf16)(acc[i][j][1] + bv),
                        (bf16)(acc[i][j][2] + bv), (bf16)(acc[i][j][3] + bv) };
          *(bf16x4*)(base + i * 16 + quad * 4) = pk;
        }
      }
    }
  }
}

// ---------- flash attention, K-split uniform blocks ----------
// grid (bh=32, j=16), 4 waves. Pass 0: chunk j, tiles [0, j+1) (unmasked half).
// Pass 1: chunk 15-j, tiles [c+1, 2c+2) (diagonal half). 17 tiles/block uniform.
// Each pass emits partial (m, l, O/l bf16) -> k_combine merges.
__global__ __launch_bounds__(256, 2) void k_attn(
    const bf16* __restrict__ Qb, const bf16* __restrict__ Kb, const bf16* __restrict__ Vt,
    bf16* __restrict__ pO0, bf16* __restrict__ pO1,
    float* __restrict__ pM, float* __restrict__ pL, const int* __restrict__ cmask)
{
  __shared__ __align__(16) char lK[2][64 * 128];
  __shared__ __align__(16) char lV[2][64 * 128];
  __shared__ __align__(16) float corr_lds[4][32];
  __shared__ __align__(16) float lrow_lds[4][32];

  const int tid = threadIdx.x, lane = tid & 63, w = tid >> 6;
  const int h = lane >> 5, q31 = lane & 31;
  const int bh = blockIdx.x;
  const int jb = blockIdx.y;
  const int causal = cmask[0];
  const float S2 = 0.18033688011112042f;  // (1/sqrt(D)) * log2(e)

  const bf16* Qh = Qb + (size_t)bh * S * D;
  const bf16* Kh = Kb + (size_t)bh * S * D;
  const bf16* Vh = Vt + (size_t)bh * D * S;

  const int so0 = w * 1024 + lane * 16;
  int srow[2], slk[2];
  #pragma unroll
  for (int p = 0; p < 2; ++p) {
    const int o = p * 4096 + so0;
    const int row = o >> 7, cbv = o & 127;
    srow[p] = row;
    slk[p] = (cbv ^ ((row & 7) << 4)) >> 1;
  }
  const int swz = (q31 & 7) << 4;

  #pragma unroll 1
  for (int pidx = 0; pidx < 2; ++pidx) {
    const int c  = pidx ? (15 - jb) : jb;
    const int t0 = causal ? (pidx ? (c + 1) : 0) : (pidx ? 16 : 0);
    const int t1 = causal ? (pidx ? (2 * c + 2) : (c + 1)) : (pidx ? 32 : 16);
    const int q0w = c * 128 + 32 * w;
    const int qg  = q0w + q31;

    __builtin_amdgcn_s_barrier();   // LDS buffers free of previous pass readers

    bf16x8 qf[4];
    #pragma unroll
    for (int ds = 0; ds < 4; ++ds)
      qf[ds] = *(const bf16x8*)(Qh + (size_t)qg * D + 16 * ds + 8 * h);

    // prologue: stage tile t0 -> buf 0
    #pragma unroll
    for (int p = 0; p < 2; ++p) {
      gload16(Kh + (size_t)(t0 * 64 + srow[p]) * D + slk[p], lK[0] + p * 4096 + so0);
      gload16(Vh + (size_t)srow[p] * S + t0 * 64 + slk[p],   lV[0] + p * 4096 + so0);
    }

    f32x16 o0 = {}, o1 = {};
    float mrun = -INFINITY, lr = 0.f;

    #pragma unroll 1
    for (int t = t0; t < t1; ++t) {
      const int cb = (t - t0) & 1;
      __builtin_amdgcn_s_barrier();
      if (t + 1 < t1) {
        const int kb = (t + 1) * 64;
        #pragma unroll
        for (int p = 0; p < 2; ++p) {
          gload16(Kh + (size_t)(kb + srow[p]) * D + slk[p], lK[cb ^ 1] + p * 4096 + so0);
          gload16(Vh + (size_t)srow[p] * S + kb + slk[p],   lV[cb ^ 1] + p * 4096 + so0);
        }
        asm volatile("s_waitcnt vmcnt(4)" ::: "memory");
      } else {
        asm volatile("s_waitcnt vmcnt(0)" ::: "memory");
      }
      __builtin_amdgcn_s_barrier();

      const bool active = !causal || (64 * t <= q0w + 31);
      if (active) {
        f32x16 s0v = {}, s1v = {};
        __builtin_amdgcn_s_setprio(1);
        #pragma unroll
        for (int ds = 0; ds < 4; ++ds) {
          const int col = (32 * ds + 16 * h) ^ swz;
          const bf16x8 kf0 = *(const bf16x8*)(lK[cb] + q31 * 128 + col);
          const bf16x8 kf1 = *(const bf16x8*)(lK[cb] + (32 + q31) * 128 + col);
          s0v = __builtin_amdgcn_mfma_f32_32x32x16_bf16(kf0, qf[ds], s0v, 0, 0, 0);
          s1v = __builtin_amdgcn_mfma_f32_32x32x16_bf16(kf1, qf[ds], s1v, 0, 0, 0);
        }
        __builtin_amdgcn_s_setprio(0);

        if (causal && (64 * t + 63 > q0w)) {
          #pragma unroll
          for (int r = 0; r < 16; ++r) {
            const int kg = 64 * t + (r & 3) + 8 * (r >> 2) + 4 * h;
            if (kg > qg)      s0v[r] = -INFINITY;
            if (kg + 32 > qg) s1v[r] = -INFINITY;
          }
        }

        float a8[8];
        #pragma unroll
        for (int i = 0; i < 8; ++i)
          a8[i] = fmaxf(fmaxf(s0v[i], s0v[i + 8]), fmaxf(s1v[i], s1v[i + 8]));
        float tmax = fmaxf(fmaxf(fmaxf(a8[0], a8[1]), fmaxf(a8[2], a8[3])),
                           fmaxf(fmaxf(a8[4], a8[5]), fmaxf(a8[6], a8[7])));
        tmax = fmaxf(tmax, __shfl_xor(tmax, 32, 64));

        const bool nogrow = __all(tmax <= mrun);
        const float mnew = nogrow ? mrun : fmaxf(mrun, tmax);
        float corrf = 1.f;
        if (!nogrow) {
          corrf = __builtin_amdgcn_exp2f((mrun - mnew) * S2);
          corr_lds[w][q31] = corrf;
        }
        const float msc = mnew * S2;

        #pragma unroll
        for (int r = 0; r < 16; ++r) {
          s0v[r] = __builtin_amdgcn_exp2f(__builtin_fmaf(s0v[r], S2, -msc));
          s1v[r] = __builtin_amdgcn_exp2f(__builtin_fmaf(s1v[r], S2, -msc));
        }

        float b8[8];
        #pragma unroll
        for (int i = 0; i < 8; ++i)
          b8[i] = (s0v[i] + s0v[i + 8]) + (s1v[i] + s1v[i + 8]);
        float psum = ((b8[0] + b8[1]) + (b8[2] + b8[3])) + ((b8[4] + b8[5]) + (b8[6] + b8[7]));
        psum += __shfl_xor(psum, 32, 64);
        lr = lr * corrf + psum;
        mrun = mnew;

        u32 pk[8][2];
        #pragma unroll
        for (int jj = 0; jj < 4; ++jj) {
          pk[jj][0]     = pack2(s0v[4 * jj],     s0v[4 * jj + 1]);
          pk[jj][1]     = pack2(s0v[4 * jj + 2], s0v[4 * jj + 3]);
          pk[jj + 4][0] = pack2(s1v[4 * jj],     s1v[4 * jj + 1]);
          pk[jj + 4][1] = pack2(s1v[4 * jj + 2], s1v[4 * jj + 3]);
        }

        if (!nogrow) {
          #pragma unroll
          for (int j = 0; j < 4; ++j) {
            const f32x4 cv = *(const f32x4*)&corr_lds[w][8 * j + 4 * h];
            #pragma unroll
            for (int sr = 0; sr < 4; ++sr) {
              o0[4 * j + sr] *= cv[sr];
              o1[4 * j + sr] *= cv[sr];
            }
          }
        }

        __builtin_amdgcn_s_setprio(1);
        #pragma unroll
        for (int ks = 0; ks < 4; ++ks) {
          u32 a0 = pk[2 * ks][0], b0 = pk[2 * ks + 1][0];
          u32 a1 = pk[2 * ks][1], b1 = pk[2 * ks + 1][1];
          asm volatile("v_permlane32_swap_b32 %0, %1" : "+v"(a0), "+v"(b0));
          asm volatile("v_permlane32_swap_b32 %0, %1" : "+v"(a1), "+v"(b1));
          FU f; f.w[0] = a0; f.w[1] = a1; f.w[2] = b0; f.w[3] = b1;
          const int col = (32 * ks + 16 * h) ^ swz;
          const bf16x8 vf0 = *(const bf16x8*)(lV[cb] + q31 * 128 + col);
          const bf16x8 vf1 = *(const bf16x8*)(lV[cb] + (32 + q31) * 128 + col);
          o0 = __builtin_amdgcn_mfma_f32_32x32x16_bf16(f.v, vf0, o0, 0, 0, 0);
          o1 = __builtin_amdgcn_mfma_f32_32x32x16_bf16(f.v, vf1, o1, 0, 0, 0);
        }
        __builtin_amdgcn_s_setprio(0);
      }
    }  // t

    // write partial: m, l (h==0 lanes) and O/l (bf16)
    if (h == 0) {
      pM[(size_t)pidx * NROWS + bh * S + qg] = mrun;
      pL[(size_t)pidx * NROWS + bh * S + qg] = lr;
    }
    lrow_lds[w][q31] = lr;
    bf16* po = pidx ? pO1 : pO0;
    #pragma unroll
    for (int j = 0; j < 4; ++j) {
      const f32x4 lv = *(const f32x4*)&lrow_lds[w][8 * j + 4 * h];
      #pragma unroll
      for (int sr = 0; sr < 4; ++sr) {
        const int r = 4 * j + sr;
        const float inv = lv[sr] > 0.f ? 1.0f / lv[sr] : 0.f;
        const int qrow = q0w + (r & 3) + 8 * (r >> 2) + 4 * h;
        bf16* dst = po + ((size_t)(bh * S + qrow)) * D;
        dst[q31]      = (bf16)(o0[r] * inv);
        dst[32 + q31] = (bf16)(o1[r] * inv);
      }
    }
  }  // pass
}

// ---------- combine two attention partials -> AO[B,S,E] ----------
__global__ __launch_bounds__(256) void k_combine(
    const bf16* __restrict__ pO0, const bf16* __restrict__ pO1,
    const float* __restrict__ pM, const float* __restrict__ pL,
    bf16* __restrict__ AO)
{
  const float S2 = 0.18033688011112042f;
  const int idx = blockIdx.x * 256 + threadIdx.x;   // NROWS * 8
  const int row = idx >> 3, d0 = (idx & 7) * 8;
  const float mA = pM[row], mB = pM[NROWS + row];
  const float lA = pL[row], lB = pL[NROWS + row];
  const float m = fmaxf(mA, mB);
  const float wA = lA > 0.f ? lA * __builtin_amdgcn_exp2f((mA - m) * S2) : 0.f;
  const float wB = lB > 0.f ? lB * __builtin_amdgcn_exp2f((mB - m) * S2) : 0.f;
  const float inv = 1.0f / (wA + wB);
  const bf16x8 a = *(const bf16x8*)(pO0 + (size_t)row * D + d0);
  const bf16x8 b = *(const bf16x8*)(pO1 + (size_t)row * D + d0);
  bf16x8 o;
  #pragma unroll
  for (int i = 0; i < 8; ++i)
    o[i] = (bf16)((wA * (float)a[i] + wB * (float)b[i]) * inv);
  const int bb = row >> 15, hh = (row >> 11) & 15, s = row & 2047;
  *(bf16x8*)(AO + ((size_t)(bb * S + s)) * E + hh * D + d0) = o;
}

extern "C" void kernel_launch(void* const* d_in, const int* in_sizes, int n_in,
                              void* d_out, int out_size, void* d_ws, size_t ws_size,
                              hipStream_t stream) {
  (void)in_sizes; (void)n_in; (void)out_size; (void)ws_size;
  const float* x     = (const float*)d_in[0];
  const float* W_in  = (const float*)d_in[1];
  const float* b_in  = (const float*)d_in[2];
  const float* W_out = (const float*)d_in[3];
  const float* b_out = (const float*)d_in[4];
  const int*   cmask = (const int*)d_in[5];

  char* ws = (char*)d_ws;
  bf16* xb    = (bf16*)ws; ws += (size_t)M * E * 2;          // 8MB (pO0 overlays after gemm0)
  bf16* wtin  = (bf16*)ws; ws += (size_t)N3 * E * 2;         // 6MB
  bf16* wtout = (bf16*)ws; ws += (size_t)E * E * 2;          // 2MB
  bf16* qB    = (bf16*)ws; ws += (size_t)B * H * S * D * 2;  // 8MB
  bf16* kB    = (bf16*)ws; ws += (size_t)B * H * S * D * 2;  // 8MB
  bf16* vT    = (bf16*)ws; ws += (size_t)B * H * S * D * 2;  // 8MB
  bf16* ao    = (bf16*)ws; ws += (size_t)M * E * 2;          // 8MB
  bf16* pO1   = (bf16*)ws; ws += (size_t)NROWS * D * 2;      // 8MB
  float* pMb  = (float*)ws; ws += (size_t)2 * NROWS * 4;     // 0.5MB
  float* pLb  = (float*)ws; ws += (size_t)2 * NROWS * 4;     // 0.5MB
  bf16* pO0   = xb;  // xb dead after gemm0

  k_cvt<<<M * E / 1024, 256, 0, stream>>>(x, xb);
  k_transpose_cvt<<<dim3(N3 / 32, E / 32), dim3(32, 8), 0, stream>>>(W_in, wtin, E, N3);
  k_transpose_cvt<<<dim3(E / 32, E / 32), dim3(32, 8), 0, stream>>>(W_out, wtout, E, E);
  k_gemm<0><<<dim3((M / 128) * (N3 / 128)), 256, 0, stream>>>(
      xb, wtin, b_in, nullptr, qB, kB, vT, E, N3);
  k_attn<<<dim3(32, 16), 256, 0, stream>>>(qB, kB, vT, pO0, pO1, pMb, pLb, cmask);
  k_combine<<<NROWS * 8 / 256, 256, 0, stream>>>(pO0, pO1, pMb, pLb, ao);
  k_gemm<1><<<dim3((M / 128) * (E / 128)), 256, 0, stream>>>(
      ao, wtout, b_out, (float*)d_out, nullptr, nullptr, nullptr, E, E);
}